// Round 1
// baseline (554.744 us; speedup 1.0000x reference)
//
#include <hip/hip_runtime.h>

// Problem constants (from reference):
//   x:           [B=32, C=2048, H=32, W=32] fp32
//   slot_assign: [B, H, W] int32 in [0, 256)
//   alpha/beta:  [256, 2048] fp32
//   out[b,c,p] = alpha[slot[b,p], c] * x[b,c,p] + beta[slot[b,p], c]  (p = h*W+w)

typedef float  f4 __attribute__((ext_vector_type(4)));
typedef int    i4 __attribute__((ext_vector_type(4)));

#define CH   2048
#define HW   1024
#define CG   (CH / 4)   // 512 channel groups per image

// One block = one (image b, channel group cg of 4 channels).
// 256 threads; thread t handles pixels 4t..4t+3 for all 4 channels.
// x/out: fully coalesced dwordx4 (wave covers 1 KiB contiguous).
// alpha/beta: float4 gathers from L2-resident 2 MiB tables.
__global__ __launch_bounds__(256) void fa_kernel(
    const float* __restrict__ x,
    const int*   __restrict__ slot,
    const float* __restrict__ alpha,
    const float* __restrict__ beta,
    float*       __restrict__ out)
{
    const int cg = blockIdx.x & (CG - 1);
    const int b  = blockIdx.x >> 9;          // /512
    const int c0 = cg << 2;
    const int p  = threadIdx.x << 2;

    // 4 slot ids for this thread's 4 pixels (coalesced int4)
    const i4 s = *(const i4*)(slot + b * HW + p);

    // per-pixel alpha/beta rows, channels c0..c0+3 (vectorized gathers, L2 hits)
    const f4 a0 = *(const f4*)(alpha + (size_t)s.x * CH + c0);
    const f4 a1 = *(const f4*)(alpha + (size_t)s.y * CH + c0);
    const f4 a2 = *(const f4*)(alpha + (size_t)s.z * CH + c0);
    const f4 a3 = *(const f4*)(alpha + (size_t)s.w * CH + c0);
    const f4 b0 = *(const f4*)(beta  + (size_t)s.x * CH + c0);
    const f4 b1 = *(const f4*)(beta  + (size_t)s.y * CH + c0);
    const f4 b2 = *(const f4*)(beta  + (size_t)s.z * CH + c0);
    const f4 b3 = *(const f4*)(beta  + (size_t)s.w * CH + c0);

    const size_t base = ((size_t)b * CH + c0) * HW + p;

#pragma unroll
    for (int j = 0; j < 4; ++j) {            // channel c0+j
        const f4 xv = __builtin_nontemporal_load((const f4*)(x + base + (size_t)j * HW));
        f4 o;
        o[0] = a0[j] * xv[0] + b0[j];
        o[1] = a1[j] * xv[1] + b1[j];
        o[2] = a2[j] * xv[2] + b2[j];
        o[3] = a3[j] * xv[3] + b3[j];
        __builtin_nontemporal_store(o, (f4*)(out + base + (size_t)j * HW));
    }
}

extern "C" void kernel_launch(void* const* d_in, const int* in_sizes, int n_in,
                              void* d_out, int out_size, void* d_ws, size_t ws_size,
                              hipStream_t stream) {
    const float* x     = (const float*)d_in[0];
    const int*   slot  = (const int*)d_in[1];
    const float* alpha = (const float*)d_in[2];
    const float* beta  = (const float*)d_in[3];
    float*       out   = (float*)d_out;

    const int B = in_sizes[0] / (CH * HW);   // 32
    dim3 grid(B * CG);                        // 32 * 512 = 16384 blocks
    dim3 block(256);
    fa_kernel<<<grid, block, 0, stream>>>(x, slot, alpha, beta, out);
}

// Round 2
// 486.766 us; speedup vs baseline: 1.1397x; 1.1397x over previous
//
#include <hip/hip_runtime.h>

// out[b,c,p] = alpha[slot[b,p], c] * x[b,c,p] + beta[slot[b,p], c]
//   x: [B=32, C=2048, HW=1024] fp32, slot: [B, 1024] int32 in [0,256)
//   alpha/beta: [256, 2048] fp32
//
// Block = (image b, channel group of 4). 256 threads.
//  - Stage alpha/beta[0..255][c0..c0+3] into LDS (8 KB) — removes the random
//    global gathers that serialized the L1/TA last round.
//  - Thread t: pixels 4t..4t+3; x/out fully-coalesced dwordx4 (1 KiB/wave).
//  - x loads issued BEFORE the barrier so HBM latency overlaps staging.

typedef float  f4 __attribute__((ext_vector_type(4)));
typedef int    i4 __attribute__((ext_vector_type(4)));

#define CH   2048
#define HW   1024
#define NS   256
#define CG   (CH / 4)   // 512 channel groups per image

__global__ __launch_bounds__(256) void fa_kernel(
    const float* __restrict__ x,
    const int*   __restrict__ slot,
    const float* __restrict__ alpha,
    const float* __restrict__ beta,
    float*       __restrict__ out)
{
    __shared__ f4 lds_a[NS];   // alpha[s][c0..c0+3], 4 KB
    __shared__ f4 lds_b[NS];   // beta [s][c0..c0+3], 4 KB

    const int cg = blockIdx.x & (CG - 1);
    const int b  = blockIdx.x >> 9;          // /512
    const int c0 = cg << 2;
    const int t  = threadIdx.x;
    const int p  = t << 2;

    // --- issue all global loads up front ---
    // slot ids for this thread's 4 pixels (coalesced int4)
    const i4 s = *(const i4*)(slot + b * HW + p);

    // streamed x (nontemporal: don't evict the L2-resident tables)
    const size_t base = ((size_t)b * CH + c0) * HW + p;
    f4 xv0 = __builtin_nontemporal_load((const f4*)(x + base + 0 * HW));
    f4 xv1 = __builtin_nontemporal_load((const f4*)(x + base + 1 * HW));
    f4 xv2 = __builtin_nontemporal_load((const f4*)(x + base + 2 * HW));
    f4 xv3 = __builtin_nontemporal_load((const f4*)(x + base + 3 * HW));

    // cooperative table staging: thread t loads row t's 16 B chunk (L2 hits)
    lds_a[t] = *(const f4*)(alpha + (size_t)t * CH + c0);
    lds_b[t] = *(const f4*)(beta  + (size_t)t * CH + c0);

    __syncthreads();

    // per-pixel table rows from LDS (ds_read_b128, ~2.9x bank conflicts, hidden)
    const f4 a0 = lds_a[s.x], a1 = lds_a[s.y], a2 = lds_a[s.z], a3 = lds_a[s.w];
    const f4 b0 = lds_b[s.x], b1 = lds_b[s.y], b2 = lds_b[s.z], b3 = lds_b[s.w];

    f4 o;
    o[0] = a0[0]*xv0[0] + b0[0]; o[1] = a1[0]*xv0[1] + b1[0];
    o[2] = a2[0]*xv0[2] + b2[0]; o[3] = a3[0]*xv0[3] + b3[0];
    __builtin_nontemporal_store(o, (f4*)(out + base + 0 * HW));

    o[0] = a0[1]*xv1[0] + b0[1]; o[1] = a1[1]*xv1[1] + b1[1];
    o[2] = a2[1]*xv1[2] + b2[1]; o[3] = a3[1]*xv1[3] + b3[1];
    __builtin_nontemporal_store(o, (f4*)(out + base + 1 * HW));

    o[0] = a0[2]*xv2[0] + b0[2]; o[1] = a1[2]*xv2[1] + b1[2];
    o[2] = a2[2]*xv2[2] + b2[2]; o[3] = a3[2]*xv2[3] + b3[2];
    __builtin_nontemporal_store(o, (f4*)(out + base + 2 * HW));

    o[0] = a0[3]*xv3[0] + b0[3]; o[1] = a1[3]*xv3[1] + b1[3];
    o[2] = a2[3]*xv3[2] + b2[3]; o[3] = a3[3]*xv3[3] + b3[3];
    __builtin_nontemporal_store(o, (f4*)(out + base + 3 * HW));
}

extern "C" void kernel_launch(void* const* d_in, const int* in_sizes, int n_in,
                              void* d_out, int out_size, void* d_ws, size_t ws_size,
                              hipStream_t stream) {
    const float* x     = (const float*)d_in[0];
    const int*   slot  = (const int*)d_in[1];
    const float* alpha = (const float*)d_in[2];
    const float* beta  = (const float*)d_in[3];
    float*       out   = (float*)d_out;

    const int B = in_sizes[0] / (CH * HW);   // 32
    dim3 grid(B * CG);                        // 16384 blocks
    dim3 block(256);
    fa_kernel<<<grid, block, 0, stream>>>(x, slot, alpha, beta, out);
}